// Round 1
// baseline (3139.459 us; speedup 1.0000x reference)
//
#include <hip/hip_runtime.h>
#include <math.h>

// Problem constants (match reference file)
#define N_NODES_C 100000
#define DIM_C     128     // DIM_MEM == DIM_TIME == DIM_EDGE
#define DMSG_C    512     // 2*DIM_MEM + DIM_EDGE + DIM_TIME
#define N_EDGES_C 200000
#define NB        16      // nodes per block (amortizes W reads from L2)

__device__ __forceinline__ float sigmoidf_(float x) { return 1.0f / (1.0f + __expf(-x)); }

// ---- Phase A: last occurrence of each node in edge order (segment_max of pos) ----
__global__ void scatter_last_kernel(const int* __restrict__ src, const int* __restrict__ dst,
                                    int* __restrict__ idx_s, int* __restrict__ idx_d) {
    int e = blockIdx.x * blockDim.x + threadIdx.x;
    if (e < N_EDGES_C) {
        atomicMax(&idx_s[src[e]], e);
        atomicMax(&idx_d[dst[e]], e);
    }
}

// ---- Phase B/C: one GRU pass. PASS=0: src update (h = original memory).
//                 PASS=1: dst update (h = out_mem after pass 0; message from ORIGINAL memory).
// 128 threads: thread j computes gate rows j (r), j+128 (z), j+256 (n) -> no reduction needed.
template <int PASS>
__global__ __launch_bounds__(128) void gru_pass_kernel(
    const float* __restrict__ memory, const float* __restrict__ last_update,
    const float* __restrict__ W_ih, const float* __restrict__ W_hh,
    const float* __restrict__ b_ih, const float* __restrict__ b_hh,
    const float* __restrict__ edge_times, const float* __restrict__ edge_feat,
    const int* __restrict__ src, const int* __restrict__ dst,
    const int* __restrict__ idx,
    float* __restrict__ out_mem, float* __restrict__ out_lu)
{
    __shared__ __align__(16) float m_lds[NB][DMSG_C];  // message per node: [self|other|ef|enc]
    __shared__ __align__(16) float h_lds[NB][DIM_C];   // GRU hidden input per node
    __shared__ int eidx[NB];

    const int t = threadIdx.x;           // 0..127
    const int base = blockIdx.x * NB;    // grid = N_NODES_C/NB exactly (100000/16 = 6250)

    // ---- build messages in LDS (coalesced: 128 threads cover DIM_C) ----
    for (int s = 0; s < NB; ++s) {
        const int n = base + s;
        const int e = idx[n];
        if (t == 0) eidx[s] = e;
        const int eu = (e >= 0) ? e : 0;            // dummy edge for inactive nodes (write masked later)
        const int other = (PASS == 0) ? dst[eu] : src[eu];
        const float mself = memory[(long)n * DIM_C + t];
        m_lds[s][t]             = mself;
        m_lds[s][DIM_C + t]     = memory[(long)other * DIM_C + t];
        m_lds[s][2 * DIM_C + t] = edge_feat[(long)eu * DIM_C + t];
        const float dt = edge_times[eu] - last_update[n];
        // w_t = 10^{-9 t/127} = exp(-ln(10)*9/127 * t)
        const float w = __expf(-0.16317532f * (float)t);
        m_lds[s][3 * DIM_C + t] = __cosf(dt * w);
        h_lds[s][t] = (PASS == 0) ? mself : out_mem[(long)n * DIM_C + t];
    }
    __syncthreads();

    // ---- gi = m @ W_ih^T for rows t, t+128, t+256 ----
    float air[NB], aiz[NB], ain[NB];
#pragma unroll
    for (int s = 0; s < NB; ++s) { air[s] = 0.0f; aiz[s] = 0.0f; ain[s] = 0.0f; }
    {
        const float4* wr = (const float4*)(W_ih + (long)t * DMSG_C);
        const float4* wz = (const float4*)(W_ih + (long)(t + 128) * DMSG_C);
        const float4* wn = (const float4*)(W_ih + (long)(t + 256) * DMSG_C);
        for (int k4 = 0; k4 < DMSG_C / 4; ++k4) {
            const float4 vr = wr[k4], vz = wz[k4], vn = wn[k4];
#pragma unroll
            for (int s = 0; s < NB; ++s) {
                const float4 mv = *(const float4*)(&m_lds[s][k4 * 4]);  // broadcast, conflict-free
                air[s] = fmaf(vr.x, mv.x, fmaf(vr.y, mv.y, fmaf(vr.z, mv.z, fmaf(vr.w, mv.w, air[s]))));
                aiz[s] = fmaf(vz.x, mv.x, fmaf(vz.y, mv.y, fmaf(vz.z, mv.z, fmaf(vz.w, mv.w, aiz[s]))));
                ain[s] = fmaf(vn.x, mv.x, fmaf(vn.y, mv.y, fmaf(vn.z, mv.z, fmaf(vn.w, mv.w, ain[s]))));
            }
        }
    }

    // ---- gh = h @ W_hh^T for rows t, t+128, t+256 ----
    float ahr[NB], ahz[NB], ahn[NB];
#pragma unroll
    for (int s = 0; s < NB; ++s) { ahr[s] = 0.0f; ahz[s] = 0.0f; ahn[s] = 0.0f; }
    {
        const float4* ur = (const float4*)(W_hh + (long)t * DIM_C);
        const float4* uz = (const float4*)(W_hh + (long)(t + 128) * DIM_C);
        const float4* un = (const float4*)(W_hh + (long)(t + 256) * DIM_C);
        for (int k4 = 0; k4 < DIM_C / 4; ++k4) {
            const float4 vr = ur[k4], vz = uz[k4], vn = un[k4];
#pragma unroll
            for (int s = 0; s < NB; ++s) {
                const float4 hv = *(const float4*)(&h_lds[s][k4 * 4]);
                ahr[s] = fmaf(vr.x, hv.x, fmaf(vr.y, hv.y, fmaf(vr.z, hv.z, fmaf(vr.w, hv.w, ahr[s]))));
                ahz[s] = fmaf(vz.x, hv.x, fmaf(vz.y, hv.y, fmaf(vz.z, hv.z, fmaf(vz.w, hv.w, ahz[s]))));
                ahn[s] = fmaf(vn.x, hv.x, fmaf(vn.y, hv.y, fmaf(vn.z, hv.z, fmaf(vn.w, hv.w, ahn[s]))));
            }
        }
    }

    // ---- GRU combine + masked write ----
    const float bir = b_ih[t], biz = b_ih[t + 128], bin_ = b_ih[t + 256];
    const float bhr = b_hh[t], bhz = b_hh[t + 128], bhn = b_hh[t + 256];
#pragma unroll
    for (int s = 0; s < NB; ++s) {
        const int n = base + s;
        const int e = eidx[s];
        const float hj = h_lds[s][t];
        if (e >= 0) {
            const float r  = sigmoidf_(air[s] + bir + ahr[s] + bhr);
            const float z  = sigmoidf_(aiz[s] + biz + ahz[s] + bhz);
            const float nn = tanhf(ain[s] + bin_ + r * (ahn[s] + bhn));
            out_mem[(long)n * DIM_C + t] = (1.0f - z) * nn + z * hj;
            if (t == 0) out_lu[n] = edge_times[e];
        } else if (PASS == 0) {
            // inactive in pass 0: d_out is poisoned, must copy original row + lu
            out_mem[(long)n * DIM_C + t] = hj;
            if (t == 0) out_lu[n] = last_update[n];
        }
        // inactive in pass 1: keep pass-0 result (already in d_out)
    }
}

extern "C" void kernel_launch(void* const* d_in, const int* in_sizes, int n_in,
                              void* d_out, int out_size, void* d_ws, size_t ws_size,
                              hipStream_t stream) {
    const float* memory      = (const float*)d_in[0];
    const float* last_update = (const float*)d_in[1];
    const float* W_ih        = (const float*)d_in[2];
    const float* W_hh        = (const float*)d_in[3];
    const float* b_ih        = (const float*)d_in[4];
    const float* b_hh        = (const float*)d_in[5];
    const float* edge_times  = (const float*)d_in[6];
    const float* edge_feat   = (const float*)d_in[7];
    const int*   src         = (const int*)d_in[8];
    const int*   dst         = (const int*)d_in[9];

    int* idx_s = (int*)d_ws;
    int* idx_d = idx_s + N_NODES_C;
    float* out_mem = (float*)d_out;
    float* out_lu  = out_mem + (size_t)N_NODES_C * DIM_C;

    // idx arrays init to -1 (0xFF bytes)
    hipMemsetAsync(d_ws, 0xFF, 2 * N_NODES_C * sizeof(int), stream);
    scatter_last_kernel<<<(N_EDGES_C + 255) / 256, 256, 0, stream>>>(src, dst, idx_s, idx_d);
    gru_pass_kernel<0><<<N_NODES_C / NB, 128, 0, stream>>>(
        memory, last_update, W_ih, W_hh, b_ih, b_hh, edge_times, edge_feat,
        src, dst, idx_s, out_mem, out_lu);
    gru_pass_kernel<1><<<N_NODES_C / NB, 128, 0, stream>>>(
        memory, last_update, W_ih, W_hh, b_ih, b_hh, edge_times, edge_feat,
        src, dst, idx_d, out_mem, out_lu);
}

// Round 2
// 653.253 us; speedup vs baseline: 4.8059x; 4.8059x over previous
//
#include <hip/hip_runtime.h>
#include <math.h>

// Problem constants (match reference file)
#define N_NODES_C 100000
#define DIM_C     128    // DIM_MEM == DIM_TIME == DIM_EDGE
#define DMSG_C    512    // 2*DIM_MEM + DIM_EDGE + DIM_TIME
#define NX        640    // X row = msg(512) + h(128)
#define N_EDGES_C 200000
#define NODES_PB  32     // nodes per block
#define LDSW      648    // padded X row in bf16 elems (+8 => +16B, bank-spread)
#define WROWS     512    // packed weight rows: r(128) z(128) i_n(128) h_n(128)

typedef __attribute__((ext_vector_type(8))) __bf16 bf16x8;
typedef __attribute__((ext_vector_type(4))) float  f32x4;

__device__ __forceinline__ float sigmoidf_(float x) { return 1.0f / (1.0f + __expf(-x)); }
__device__ __forceinline__ unsigned short f2bf(float x) {
    union { float f; unsigned u; } v; v.f = x;
    unsigned r = v.u + 0x7FFFu + ((v.u >> 16) & 1u);   // RNE
    return (unsigned short)(r >> 16);
}

// ---- Phase A: last occurrence of each node in edge order ----
__global__ void scatter_last_kernel(const int* __restrict__ src, const int* __restrict__ dst,
                                    int* __restrict__ idx_s, int* __restrict__ idx_d) {
    int e = blockIdx.x * blockDim.x + threadIdx.x;
    if (e < N_EDGES_C) {
        atomicMax(&idx_s[src[e]], e);
        atomicMax(&idx_d[dst[e]], e);
    }
}

// ---- Phase B: pack weights to bf16 Wall[512][640] ----
// rows   0..255: [W_ih_r/z | W_hh_r/z]   (K range 0..639)
// rows 256..383: [W_ih_n   | 0      ]    (K range 0..511)
// rows 384..511: [0        | W_hh_n ]    (K range 512..639)
__global__ void build_wall_kernel(const float* __restrict__ W_ih, const float* __restrict__ W_hh,
                                  unsigned short* __restrict__ Wall) {
    int i = blockIdx.x * 256 + threadIdx.x;
    if (i >= WROWS * NX) return;
    int r = i / NX, k = i - r * NX;
    float v;
    if (r < 256)      v = (k < 512) ? W_ih[(long)r * DMSG_C + k] : W_hh[(long)r * DIM_C + (k - 512)];
    else if (r < 384) v = (k < 512) ? W_ih[(long)r * DMSG_C + k] : 0.0f;
    else              v = (k >= 512) ? W_hh[(long)(r - 128) * DIM_C + (k - 512)] : 0.0f;
    Wall[i] = f2bf(v);
}

// ---- Phase C/D: fused gather + MFMA GEMM + GRU epilogue, one pass ----
// PASS=0: src update (h = original memory). PASS=1: dst update (h = out_mem).
// Block: 256 threads = 4 waves, 32 nodes. Wave w owns gate-tiles T = w+4i, i=0..7:
//   i 0..3 -> r/z combined (K 0..639), i 4..5 -> i_n (K 0..511), i 6..7 -> h_n (K 512..639)
template <int PASS>
__global__ __launch_bounds__(256) void gru_mfma_kernel(
    const float* __restrict__ memory, const float* __restrict__ last_update,
    const unsigned short* __restrict__ Wall,
    const float* __restrict__ b_ih, const float* __restrict__ b_hh,
    const float* __restrict__ edge_times, const float* __restrict__ edge_feat,
    const int* __restrict__ src, const int* __restrict__ dst,
    const int* __restrict__ idx,
    float* __restrict__ out_mem, float* __restrict__ out_lu)
{
    __shared__ __align__(16) unsigned short Xl[NODES_PB][LDSW];
    __shared__ int eidx[NODES_PB];

    const int t = threadIdx.x;
    const int base = blockIdx.x * NODES_PB;   // grid = 100000/32 = 3125 exact

    if (t < NODES_PB) eidx[t] = idx[base + t];
    __syncthreads();

    // ---- gather: build X = [self|other|ef|enc|h] in bf16 LDS ----
    const int tt = t & 127;
    const int sh = t >> 7;                    // wave-uniform (waves 0,1 -> 0; 2,3 -> 1)
    const float wfreq = __expf(-0.16317532f * (float)tt);  // 10^(-9*tt/127)
    for (int s0 = 0; s0 < NODES_PB; s0 += 2) {
        const int s = s0 + sh;
        const int n = base + s;
        const int e = eidx[s];
        const int eu = (e >= 0) ? e : 0;      // dummy edge for inactive nodes
        const int other = (PASS == 0) ? dst[eu] : src[eu];
        const float mself = memory[(long)n * DIM_C + tt];
        const float moth  = memory[(long)other * DIM_C + tt];
        const float ef    = edge_feat[(long)eu * DIM_C + tt];
        const float dt    = edge_times[eu] - last_update[n];
        const float enc   = __cosf(dt * wfreq);
        const float hv    = (PASS == 0) ? mself : out_mem[(long)n * DIM_C + tt];
        Xl[s][tt]       = f2bf(mself);
        Xl[s][128 + tt] = f2bf(moth);
        Xl[s][256 + tt] = f2bf(ef);
        Xl[s][384 + tt] = f2bf(enc);
        Xl[s][512 + tt] = f2bf(hv);
    }
    __syncthreads();

    // ---- MFMA GEMM: C[node][gate] = X @ Wall^T ----
    const int w = t >> 6, lane = t & 63;
    const int quad = lane >> 4, c = lane & 15;

    f32x4 acc[8][2];
#pragma unroll
    for (int i = 0; i < 8; ++i)
#pragma unroll
        for (int mt = 0; mt < 2; ++mt) acc[i][mt] = (f32x4){0.f, 0.f, 0.f, 0.f};

    const unsigned short* wrow[8];
#pragma unroll
    for (int i = 0; i < 8; ++i)
        wrow[i] = Wall + (long)((w + 4 * i) * 16 + c) * NX + quad * 8;

    // K 0..511: tiles 0..3 (rz) + 4,5 (i_n)
    for (int kk = 0; kk < 16; ++kk) {
        const int k0 = kk * 32;
        bf16x8 a0 = *(const bf16x8*)&Xl[c][k0 + quad * 8];
        bf16x8 a1 = *(const bf16x8*)&Xl[16 + c][k0 + quad * 8];
#pragma unroll
        for (int i = 0; i < 6; ++i) {
            bf16x8 b = *(const bf16x8*)(wrow[i] + k0);
            acc[i][0] = __builtin_amdgcn_mfma_f32_16x16x32_bf16(a0, b, acc[i][0], 0, 0, 0);
            acc[i][1] = __builtin_amdgcn_mfma_f32_16x16x32_bf16(a1, b, acc[i][1], 0, 0, 0);
        }
    }
    // K 512..639: tiles 0..3 (rz) + 6,7 (h_n)
    for (int kk = 16; kk < 20; ++kk) {
        const int k0 = kk * 32;
        bf16x8 a0 = *(const bf16x8*)&Xl[c][k0 + quad * 8];
        bf16x8 a1 = *(const bf16x8*)&Xl[16 + c][k0 + quad * 8];
#pragma unroll
        for (int ii = 0; ii < 6; ++ii) {
            const int i = (ii < 4) ? ii : ii + 2;
            bf16x8 b = *(const bf16x8*)(wrow[i] + k0);
            acc[i][0] = __builtin_amdgcn_mfma_f32_16x16x32_bf16(a0, b, acc[i][0], 0, 0, 0);
            acc[i][1] = __builtin_amdgcn_mfma_f32_16x16x32_bf16(a1, b, acc[i][1], 0, 0, 0);
        }
    }

    // ---- GRU epilogue ----
    // Lane owns (node = base + mt*16 + quad*4 + reg, dim j = (w+4p)*16 + c).
    // r = acc[p], z = acc[p+2], i_n = acc[p+4], h_n = acc[p+6].
    const float* hsrc = (PASS == 0) ? memory : out_mem;   // fp32 h for the z*h passthrough
#pragma unroll
    for (int p = 0; p < 2; ++p) {
        const int j = (w + 4 * p) * 16 + c;   // 0..127
        const float br = b_ih[j] + b_hh[j];
        const float bz = b_ih[128 + j] + b_hh[128 + j];
        const float bi = b_ih[256 + j];
        const float bh = b_hh[256 + j];
#pragma unroll
        for (int mt = 0; mt < 2; ++mt) {
#pragma unroll
            for (int reg = 0; reg < 4; ++reg) {
                const int ml = mt * 16 + quad * 4 + reg;
                const int n = base + ml;
                const int e = eidx[ml];
                const float h = hsrc[(long)n * DIM_C + j];
                if (e >= 0) {
                    const float r  = sigmoidf_(acc[p][mt][reg] + br);
                    const float z  = sigmoidf_(acc[p + 2][mt][reg] + bz);
                    const float nn = tanhf(acc[p + 4][mt][reg] + bi + r * (acc[p + 6][mt][reg] + bh));
                    out_mem[(long)n * DIM_C + j] = (1.0f - z) * nn + z * h;
                } else if (PASS == 0) {
                    out_mem[(long)n * DIM_C + j] = h;   // copy original row (d_out is poisoned)
                }
                // PASS==1 inactive: keep pass-0 result
            }
        }
    }

    if (t < NODES_PB) {
        const int n = base + t;
        const int e = eidx[t];
        if (e >= 0)            out_lu[n] = edge_times[e];
        else if (PASS == 0)    out_lu[n] = last_update[n];
    }
}

extern "C" void kernel_launch(void* const* d_in, const int* in_sizes, int n_in,
                              void* d_out, int out_size, void* d_ws, size_t ws_size,
                              hipStream_t stream) {
    const float* memory      = (const float*)d_in[0];
    const float* last_update = (const float*)d_in[1];
    const float* W_ih        = (const float*)d_in[2];
    const float* W_hh        = (const float*)d_in[3];
    const float* b_ih        = (const float*)d_in[4];
    const float* b_hh        = (const float*)d_in[5];
    const float* edge_times  = (const float*)d_in[6];
    const float* edge_feat   = (const float*)d_in[7];
    const int*   src         = (const int*)d_in[8];
    const int*   dst         = (const int*)d_in[9];

    int* idx_s = (int*)d_ws;
    int* idx_d = idx_s + N_NODES_C;
    unsigned short* Wall = (unsigned short*)((char*)d_ws + 2 * N_NODES_C * sizeof(int)); // +800KB, 16B aligned
    float* out_mem = (float*)d_out;
    float* out_lu  = out_mem + (size_t)N_NODES_C * DIM_C;

    hipMemsetAsync(d_ws, 0xFF, 2 * N_NODES_C * sizeof(int), stream);  // idx arrays = -1
    scatter_last_kernel<<<(N_EDGES_C + 255) / 256, 256, 0, stream>>>(src, dst, idx_s, idx_d);
    build_wall_kernel<<<(WROWS * NX + 255) / 256, 256, 0, stream>>>(W_ih, W_hh, Wall);
    gru_mfma_kernel<0><<<N_NODES_C / NODES_PB, 256, 0, stream>>>(
        memory, last_update, Wall, b_ih, b_hh, edge_times, edge_feat,
        src, dst, idx_s, out_mem, out_lu);
    gru_mfma_kernel<1><<<N_NODES_C / NODES_PB, 256, 0, stream>>>(
        memory, last_update, Wall, b_ih, b_hh, edge_times, edge_feat,
        src, dst, idx_d, out_mem, out_lu);
}

// Round 3
// 563.819 us; speedup vs baseline: 5.5682x; 1.1586x over previous
//
#include <hip/hip_runtime.h>
#include <math.h>

// Problem constants (match reference file)
#define N_NODES_C 100000
#define DIM_C     128
#define DMSG_C    512
#define N_EDGES_C 200000

// GEMM geometry: 64 nodes/block (4 node-groups of 16), 512 gate rows = 32 tiles
#define GROUPS_PAD 6252            // 1563 blocks * 4 groups
#define NODES_PAD  (GROUPS_PAD*16) // 100032
#define XKK 12                     // X = [self|other|ef] = 384 cols = 12 kk-chunks of 32

typedef __attribute__((ext_vector_type(8))) __bf16 bf16x8;
typedef __attribute__((ext_vector_type(4))) float  f32x4;

__device__ __forceinline__ float sigmoidf_(float x) { return 1.0f / (1.0f + __expf(-x)); }
__device__ __forceinline__ unsigned short f2bf(float x) {
    union { float f; unsigned u; } v; v.f = x;
    unsigned r = v.u + 0x7FFFu + ((v.u >> 16) & 1u);   // RNE
    return (unsigned short)(r >> 16);
}
__device__ __forceinline__ void st8(void* p, float4 lo, float4 hi) {
    union { bf16x8 v; unsigned short u[8]; } r;
    r.u[0] = f2bf(lo.x); r.u[1] = f2bf(lo.y); r.u[2] = f2bf(lo.z); r.u[3] = f2bf(lo.w);
    r.u[4] = f2bf(hi.x); r.u[5] = f2bf(hi.y); r.u[6] = f2bf(hi.z); r.u[7] = f2bf(hi.w);
    *(bf16x8*)p = r.v;
}

// ---- last occurrence of each node in edge order ----
__global__ void scatter_last_kernel(const int* __restrict__ src, const int* __restrict__ dst,
                                    int* __restrict__ idx_s, int* __restrict__ idx_d) {
    int e = blockIdx.x * blockDim.x + threadIdx.x;
    if (e < N_EDGES_C) {
        atomicMax(&idx_s[src[e]], e);
        atomicMax(&idx_d[dst[e]], e);
    }
}

// =====================  MAIN (split) PATH  =====================
// Wsw[tile][kk][lane][8]: B-fragment order. tile T: packed gate rows T*16+(l&15):
//   rows 0..127 r, 128..255 z, 256..383 i_n (W_ih), 384..511 h_n (W_hh rows 256..383)
// K map: 0..127 self, 128..255 other, 256..383 ef, 384..511 enc, 512..639 h
__global__ void build_wallsw_kernel(const float* __restrict__ W_ih, const float* __restrict__ W_hh,
                                    unsigned short* __restrict__ Wsw) {
    int id = blockIdx.x * 256 + threadIdx.x;           // 32*20*64 = 40960
    if (id >= 32 * 20 * 64) return;
    int tile = id / 1280, r = id - tile * 1280, kk = r >> 6, l = r & 63;
    int pr = tile * 16 + (l & 15);
    int k0 = kk * 32 + ((l >> 4) & 3) * 8;
    float v[8];
#pragma unroll
    for (int j = 0; j < 8; ++j) {
        int k = k0 + j;
        if (pr < 256)      v[j] = (k < 512) ? W_ih[(long)pr * DMSG_C + k] : W_hh[(long)pr * DIM_C + (k - 512)];
        else if (pr < 384) v[j] = (k < 512) ? W_ih[(long)pr * DMSG_C + k] : 0.0f;
        else               v[j] = (k >= 512) ? W_hh[(long)(pr - 128) * DIM_C + (k - 512)] : 0.0f;
    }
    union { bf16x8 bv; unsigned short u[8]; } o;
#pragma unroll
    for (int j = 0; j < 8; ++j) o.u[j] = f2bf(v[j]);
    *(bf16x8*)((char*)Wsw + ((size_t)(tile * 20 + kk) << 10) + ((size_t)l << 4)) = o.bv;
}

// Gather: 16 nodes/block. Builds Xs/Xd (A-frag-swizzled bf16), dt arrays, out_lu,
// and the inactive-pass0 copy of memory into out_mem.
__global__ __launch_bounds__(256) void gather_kernel(
    const float* __restrict__ memory, const float* __restrict__ last_update,
    const float* __restrict__ edge_times, const float* __restrict__ edge_feat,
    const int* __restrict__ src, const int* __restrict__ dst,
    const int* __restrict__ idx_s, const int* __restrict__ idx_d,
    float* __restrict__ dt_s, float* __restrict__ dt_d,
    unsigned short* __restrict__ Xs, unsigned short* __restrict__ Xd,
    float* __restrict__ out_mem, float* __restrict__ out_lu)
{
    __shared__ int es_l[16], ed_l[16], os_l[16], od_l[16];
    const int t = threadIdx.x;
    const int base = blockIdx.x * 16;
    if (t < 16) {
        const int n = base + t;
        const int es = idx_s[n], ed = idx_d[n];
        const int eus = es < 0 ? 0 : es, eud = ed < 0 ? 0 : ed;
        es_l[t] = es; ed_l[t] = ed;
        os_l[t] = dst[eus]; od_l[t] = src[eud];
        const float lun = last_update[n];
        const float ts = edge_times[eus], td = edge_times[eud];
        dt_s[n] = ts - lun; dt_d[n] = td - lun;
        out_lu[n] = (ed >= 0) ? td : ((es >= 0) ? ts : lun);
    }
    __syncthreads();
    const int m = t & 15, q = t >> 4;                  // node-in-block, col-chunk (8 cols)
    const int n = base + m;
    const size_t g = blockIdx.x;                       // node-group == block
    const int es = es_l[m];
    const int eus = (es < 0) ? 0 : es;
    const int eud = (ed_l[m] < 0) ? 0 : ed_l[m];
    const float4* self_p = (const float4*)(memory + (size_t)n * DIM_C + q * 8);
    const float4* oS_p   = (const float4*)(memory + (size_t)os_l[m] * DIM_C + q * 8);
    const float4* oD_p   = (const float4*)(memory + (size_t)od_l[m] * DIM_C + q * 8);
    const float4* eS_p   = (const float4*)(edge_feat + (size_t)eus * DIM_C + q * 8);
    const float4* eD_p   = (const float4*)(edge_feat + (size_t)eud * DIM_C + q * 8);
    float4 s0 = self_p[0], s1 = self_p[1];
    float4 a0 = oS_p[0],   a1 = oS_p[1];
    float4 b0 = oD_p[0],   b1 = oD_p[1];
    float4 c0 = eS_p[0],   c1 = eS_p[1];
    float4 d0 = eD_p[0],   d1 = eD_p[1];
    const int kkq = q >> 2;
    const size_t laneoff = (size_t)(((q & 3) * 16 + m)) << 4;
    char* XsB = (char*)Xs; char* XdB = (char*)Xd;
#define XOFF(kk) ((((g * XKK) + (kk)) << 10) + laneoff)
    st8(XsB + XOFF(kkq),     s0, s1);
    st8(XsB + XOFF(4 + kkq), a0, a1);
    st8(XsB + XOFF(8 + kkq), c0, c1);
    st8(XdB + XOFF(kkq),     s0, s1);
    st8(XdB + XOFF(4 + kkq), b0, b1);
    st8(XdB + XOFF(8 + kkq), d0, d1);
#undef XOFF
    if (es < 0) {   // inactive in pass0: seed out_mem with original memory row
        float4* op = (float4*)(out_mem + (size_t)n * DIM_C + q * 8);
        op[0] = s0; op[1] = s1;
    }
}

// GEMM+GRU pass. 256 thr = 4 independent waves over the same 64 nodes.
// Wave w owns gate-tiles {w,w+4,w+8,w+12,w+16,w+20,w+24,w+28} = slots
// {r0,r1,z0,z1,i0,i1,h0,h1}. No LDS, no barriers.
template <int PASS>
__global__ __launch_bounds__(256, 2) void gemm_pass_kernel(
    const float* __restrict__ memory,
    const unsigned short* __restrict__ Wsw,
    const float* __restrict__ b_ih, const float* __restrict__ b_hh,
    const unsigned short* __restrict__ Xsw,
    const float* __restrict__ dtp, const int* __restrict__ idxp,
    float* __restrict__ out_mem)
{
    const int t = threadIdx.x;
    const int w = t >> 6, lane = t & 63, quad = lane >> 4, c = lane & 15;
    const long g0 = (long)blockIdx.x * 4;
    const char* Xb = (const char*)Xsw;
    const char* Wb = (const char*)Wsw;
    const size_t laneoff = (size_t)lane << 4;

    f32x4 acc[8][4];
#pragma unroll
    for (int s = 0; s < 8; ++s)
#pragma unroll
        for (int nt = 0; nt < 4; ++nt) acc[s][nt] = (f32x4){0.f, 0.f, 0.f, 0.f};

    // Phase X: kk 0..11 (slots 0..5: r0 r1 z0 z1 i0 i1)
    for (int kk = 0; kk < XKK; ++kk) {
        bf16x8 A[4];
#pragma unroll
        for (int nt = 0; nt < 4; ++nt)
            A[nt] = *(const bf16x8*)(Xb + (((g0 + nt) * XKK + kk) << 10) + laneoff);
#pragma unroll
        for (int s = 0; s < 6; ++s) {
            const int tile = w + 4 * s;
            bf16x8 B = *(const bf16x8*)(Wb + ((size_t)(tile * 20 + kk) << 10) + laneoff);
#pragma unroll
            for (int nt = 0; nt < 4; ++nt)
                acc[s][nt] = __builtin_amdgcn_mfma_f32_16x16x32_bf16(A[nt], B, acc[s][nt], 0, 0, 0);
        }
    }

    // Phase ENC: kk 12..15, A = cos(dt * w_f) computed in-register
    float dtv[4];
#pragma unroll
    for (int nt = 0; nt < 4; ++nt) dtv[nt] = dtp[(g0 + nt) * 16 + c];
    for (int kk = 12; kk < 16; ++kk) {
        const int f0 = (kk - 12) * 32 + quad * 8;
        float wf[8];
#pragma unroll
        for (int j = 0; j < 8; ++j) wf[j] = __expf(-0.16317532f * (float)(f0 + j));
        bf16x8 A[4];
#pragma unroll
        for (int nt = 0; nt < 4; ++nt) {
            union { bf16x8 v; unsigned short u[8]; } r;
#pragma unroll
            for (int j = 0; j < 8; ++j) r.u[j] = f2bf(__cosf(dtv[nt] * wf[j]));
            A[nt] = r.v;
        }
#pragma unroll
        for (int s = 0; s < 6; ++s) {
            const int tile = w + 4 * s;
            bf16x8 B = *(const bf16x8*)(Wb + ((size_t)(tile * 20 + kk) << 10) + laneoff);
#pragma unroll
            for (int nt = 0; nt < 4; ++nt)
                acc[s][nt] = __builtin_amdgcn_mfma_f32_16x16x32_bf16(A[nt], B, acc[s][nt], 0, 0, 0);
        }
    }

    // Phase H: kk 16..19. PASS0: h == memory == X self block (kk-16). PASS1: h = out_mem fp32.
    for (int kk = 16; kk < 20; ++kk) {
        bf16x8 A[4];
        if (PASS == 0) {
#pragma unroll
            for (int nt = 0; nt < 4; ++nt)
                A[nt] = *(const bf16x8*)(Xb + (((g0 + nt) * XKK + (kk - 16)) << 10) + laneoff);
        } else {
#pragma unroll
            for (int nt = 0; nt < 4; ++nt) {
                long row = (g0 + nt) * 16 + c;
                if (row >= N_NODES_C) row = N_NODES_C - 1;   // clamp (stores masked anyway)
                const float4* hp = (const float4*)(out_mem + (size_t)row * DIM_C + (kk - 16) * 32 + quad * 8);
                float4 lo = hp[0], hi = hp[1];
                union { bf16x8 v; unsigned short u[8]; } r;
                r.u[0] = f2bf(lo.x); r.u[1] = f2bf(lo.y); r.u[2] = f2bf(lo.z); r.u[3] = f2bf(lo.w);
                r.u[4] = f2bf(hi.x); r.u[5] = f2bf(hi.y); r.u[6] = f2bf(hi.z); r.u[7] = f2bf(hi.w);
                A[nt] = r.v;
            }
        }
#pragma unroll
        for (int s6 = 0; s6 < 6; ++s6) {
            const int s = (s6 < 4) ? s6 : s6 + 2;            // slots 0,1,2,3,6,7
            const int tile = w + 4 * s;
            bf16x8 B = *(const bf16x8*)(Wb + ((size_t)(tile * 20 + kk) << 10) + laneoff);
#pragma unroll
            for (int nt = 0; nt < 4; ++nt)
                acc[s][nt] = __builtin_amdgcn_mfma_f32_16x16x32_bf16(A[nt], B, acc[s][nt], 0, 0, 0);
        }
    }

    // Epilogue: lane owns node = (g0+nt)*16 + quad*4 + reg, dims j = (w+4p)*16 + c
    const float* hsrc = (PASS == 0) ? memory : out_mem;
#pragma unroll
    for (int p = 0; p < 2; ++p) {
        const int j = (w + 4 * p) * 16 + c;
        const float br = b_ih[j] + b_hh[j];
        const float bz = b_ih[128 + j] + b_hh[128 + j];
        const float bi = b_ih[256 + j];
        const float bh = b_hh[256 + j];
#pragma unroll
        for (int nt = 0; nt < 4; ++nt) {
#pragma unroll
            for (int reg = 0; reg < 4; ++reg) {
                const long n = (g0 + nt) * 16 + quad * 4 + reg;
                if (n < N_NODES_C) {
                    const int e = idxp[n];
                    if (e >= 0) {
                        const float r  = sigmoidf_(acc[0 + p][nt][reg] + br);
                        const float z  = sigmoidf_(acc[2 + p][nt][reg] + bz);
                        const float nn = tanhf(acc[4 + p][nt][reg] + bi + r * (acc[6 + p][nt][reg] + bh));
                        const float h  = hsrc[(size_t)n * DIM_C + j];
                        out_mem[(size_t)n * DIM_C + j] = (1.0f - z) * nn + z * h;
                    }
                }
            }
        }
    }
}

// =====================  FALLBACK (R2 fused) PATH  =====================
#define NODES_PB  32
#define LDSW      648
#define WROWS     512
#define NXF       640

__global__ void build_wall_kernel(const float* __restrict__ W_ih, const float* __restrict__ W_hh,
                                  unsigned short* __restrict__ Wall) {
    int i = blockIdx.x * 256 + threadIdx.x;
    if (i >= WROWS * NXF) return;
    int r = i / NXF, k = i - r * NXF;
    float v;
    if (r < 256)      v = (k < 512) ? W_ih[(long)r * DMSG_C + k] : W_hh[(long)r * DIM_C + (k - 512)];
    else if (r < 384) v = (k < 512) ? W_ih[(long)r * DMSG_C + k] : 0.0f;
    else              v = (k >= 512) ? W_hh[(long)(r - 128) * DIM_C + (k - 512)] : 0.0f;
    Wall[i] = f2bf(v);
}

template <int PASS>
__global__ __launch_bounds__(256) void gru_mfma_kernel(
    const float* __restrict__ memory, const float* __restrict__ last_update,
    const unsigned short* __restrict__ Wall,
    const float* __restrict__ b_ih, const float* __restrict__ b_hh,
    const float* __restrict__ edge_times, const float* __restrict__ edge_feat,
    const int* __restrict__ src, const int* __restrict__ dst,
    const int* __restrict__ idx,
    float* __restrict__ out_mem, float* __restrict__ out_lu)
{
    __shared__ __align__(16) unsigned short Xl[NODES_PB][LDSW];
    __shared__ int eidx[NODES_PB];
    const int t = threadIdx.x;
    const int base = blockIdx.x * NODES_PB;
    if (t < NODES_PB) eidx[t] = idx[base + t];
    __syncthreads();
    const int tt = t & 127;
    const int sh = t >> 7;
    const float wfreq = __expf(-0.16317532f * (float)tt);
    for (int s0 = 0; s0 < NODES_PB; s0 += 2) {
        const int s = s0 + sh;
        const int n = base + s;
        const int e = eidx[s];
        const int eu = (e >= 0) ? e : 0;
        const int other = (PASS == 0) ? dst[eu] : src[eu];
        const float mself = memory[(long)n * DIM_C + tt];
        const float moth  = memory[(long)other * DIM_C + tt];
        const float ef    = edge_feat[(long)eu * DIM_C + tt];
        const float dt    = edge_times[eu] - last_update[n];
        const float enc   = __cosf(dt * wfreq);
        const float hv    = (PASS == 0) ? mself : out_mem[(long)n * DIM_C + tt];
        Xl[s][tt]       = f2bf(mself);
        Xl[s][128 + tt] = f2bf(moth);
        Xl[s][256 + tt] = f2bf(ef);
        Xl[s][384 + tt] = f2bf(enc);
        Xl[s][512 + tt] = f2bf(hv);
    }
    __syncthreads();
    const int w = t >> 6, lane = t & 63;
    const int quad = lane >> 4, c = lane & 15;
    f32x4 acc[8][2];
#pragma unroll
    for (int i = 0; i < 8; ++i)
#pragma unroll
        for (int mt = 0; mt < 2; ++mt) acc[i][mt] = (f32x4){0.f, 0.f, 0.f, 0.f};
    const unsigned short* wrow[8];
#pragma unroll
    for (int i = 0; i < 8; ++i)
        wrow[i] = Wall + (long)((w + 4 * i) * 16 + c) * NXF + quad * 8;
    for (int kk = 0; kk < 16; ++kk) {
        const int k0 = kk * 32;
        bf16x8 a0 = *(const bf16x8*)&Xl[c][k0 + quad * 8];
        bf16x8 a1 = *(const bf16x8*)&Xl[16 + c][k0 + quad * 8];
#pragma unroll
        for (int i = 0; i < 6; ++i) {
            bf16x8 b = *(const bf16x8*)(wrow[i] + k0);
            acc[i][0] = __builtin_amdgcn_mfma_f32_16x16x32_bf16(a0, b, acc[i][0], 0, 0, 0);
            acc[i][1] = __builtin_amdgcn_mfma_f32_16x16x32_bf16(a1, b, acc[i][1], 0, 0, 0);
        }
    }
    for (int kk = 16; kk < 20; ++kk) {
        const int k0 = kk * 32;
        bf16x8 a0 = *(const bf16x8*)&Xl[c][k0 + quad * 8];
        bf16x8 a1 = *(const bf16x8*)&Xl[16 + c][k0 + quad * 8];
#pragma unroll
        for (int ii = 0; ii < 6; ++ii) {
            const int i = (ii < 4) ? ii : ii + 2;
            bf16x8 b = *(const bf16x8*)(wrow[i] + k0);
            acc[i][0] = __builtin_amdgcn_mfma_f32_16x16x32_bf16(a0, b, acc[i][0], 0, 0, 0);
            acc[i][1] = __builtin_amdgcn_mfma_f32_16x16x32_bf16(a1, b, acc[i][1], 0, 0, 0);
        }
    }
    const float* hsrc = (PASS == 0) ? memory : out_mem;
#pragma unroll
    for (int p = 0; p < 2; ++p) {
        const int j = (w + 4 * p) * 16 + c;
        const float br = b_ih[j] + b_hh[j];
        const float bz = b_ih[128 + j] + b_hh[128 + j];
        const float bi = b_ih[256 + j];
        const float bh = b_hh[256 + j];
#pragma unroll
        for (int mt = 0; mt < 2; ++mt) {
#pragma unroll
            for (int reg = 0; reg < 4; ++reg) {
                const int ml = mt * 16 + quad * 4 + reg;
                const int n = base + ml;
                const int e = eidx[ml];
                const float h = hsrc[(long)n * DIM_C + j];
                if (e >= 0) {
                    const float r  = sigmoidf_(acc[p][mt][reg] + br);
                    const float z  = sigmoidf_(acc[p + 2][mt][reg] + bz);
                    const float nn = tanhf(acc[p + 4][mt][reg] + bi + r * (acc[p + 6][mt][reg] + bh));
                    out_mem[(long)n * DIM_C + j] = (1.0f - z) * nn + z * h;
                } else if (PASS == 0) {
                    out_mem[(long)n * DIM_C + j] = h;
                }
            }
        }
    }
    if (t < NODES_PB) {
        const int n = base + t;
        const int e = eidx[t];
        if (e >= 0)         out_lu[n] = edge_times[e];
        else if (PASS == 0) out_lu[n] = last_update[n];
    }
}

// =====================  LAUNCH  =====================
extern "C" void kernel_launch(void* const* d_in, const int* in_sizes, int n_in,
                              void* d_out, int out_size, void* d_ws, size_t ws_size,
                              hipStream_t stream) {
    const float* memory      = (const float*)d_in[0];
    const float* last_update = (const float*)d_in[1];
    const float* W_ih        = (const float*)d_in[2];
    const float* W_hh        = (const float*)d_in[3];
    const float* b_ih        = (const float*)d_in[4];
    const float* b_hh        = (const float*)d_in[5];
    const float* edge_times  = (const float*)d_in[6];
    const float* edge_feat   = (const float*)d_in[7];
    const int*   src         = (const int*)d_in[8];
    const int*   dst         = (const int*)d_in[9];

    float* out_mem = (float*)d_out;
    float* out_lu  = out_mem + (size_t)N_NODES_C * DIM_C;

    // ws layout (main path)
    const size_t sIdx  = (size_t)NODES_PAD * 4;           // 400128 B each
    const size_t sDt   = (size_t)NODES_PAD * 4;
    const size_t sWall = (size_t)32 * 20 * 1024;          // 655360 B
    const size_t sX    = (size_t)GROUPS_PAD * XKK * 1024; // 76.8 MB each
    const size_t oIdxS = 0, oIdxD = oIdxS + sIdx, oDtS = oIdxD + sIdx, oDtD = oDtS + sDt;
    const size_t oWall = oDtD + sDt, oXs = oWall + sWall, oXd = oXs + sX;
    const size_t need  = oXd + sX;                        // ~149 MB

    if (ws_size >= need) {
        int* idx_s = (int*)((char*)d_ws + oIdxS);
        int* idx_d = (int*)((char*)d_ws + oIdxD);
        float* dt_s = (float*)((char*)d_ws + oDtS);
        float* dt_d = (float*)((char*)d_ws + oDtD);
        unsigned short* Wsw = (unsigned short*)((char*)d_ws + oWall);
        unsigned short* Xs  = (unsigned short*)((char*)d_ws + oXs);
        unsigned short* Xd  = (unsigned short*)((char*)d_ws + oXd);

        hipMemsetAsync(d_ws, 0xFF, 2 * sIdx, stream);     // idx arrays = -1
        scatter_last_kernel<<<(N_EDGES_C + 255) / 256, 256, 0, stream>>>(src, dst, idx_s, idx_d);
        build_wallsw_kernel<<<160, 256, 0, stream>>>(W_ih, W_hh, Wsw);
        gather_kernel<<<N_NODES_C / 16, 256, 0, stream>>>(
            memory, last_update, edge_times, edge_feat, src, dst,
            idx_s, idx_d, dt_s, dt_d, Xs, Xd, out_mem, out_lu);
        gemm_pass_kernel<0><<<GROUPS_PAD / 4, 256, 0, stream>>>(
            memory, Wsw, b_ih, b_hh, Xs, dt_s, idx_s, out_mem);
        gemm_pass_kernel<1><<<GROUPS_PAD / 4, 256, 0, stream>>>(
            memory, Wsw, b_ih, b_hh, Xd, dt_d, idx_d, out_mem);
    } else {
        // R2 fused fallback (needs ~1.5 MB ws)
        int* idx_s = (int*)d_ws;
        int* idx_d = idx_s + N_NODES_C;
        unsigned short* Wall = (unsigned short*)((char*)d_ws + 2 * N_NODES_C * sizeof(int));
        hipMemsetAsync(d_ws, 0xFF, 2 * N_NODES_C * sizeof(int), stream);
        scatter_last_kernel<<<(N_EDGES_C + 255) / 256, 256, 0, stream>>>(src, dst, idx_s, idx_d);
        build_wall_kernel<<<(WROWS * NXF + 255) / 256, 256, 0, stream>>>(W_ih, W_hh, Wall);
        gru_mfma_kernel<0><<<N_NODES_C / NODES_PB, 256, 0, stream>>>(
            memory, last_update, Wall, b_ih, b_hh, edge_times, edge_feat,
            src, dst, idx_s, out_mem, out_lu);
        gru_mfma_kernel<1><<<N_NODES_C / NODES_PB, 256, 0, stream>>>(
            memory, last_update, Wall, b_ih, b_hh, edge_times, edge_feat,
            src, dst, idx_d, out_mem, out_lu);
    }
}